// Round 2
// baseline (1119.932 us; speedup 1.0000x reference)
//
#include <hip/hip_runtime.h>
#include <cstdint>
#include <cstddef>

#define B_ 2
#define N_ 384
#define D_ 128
#define NN (N_*N_)                  // 147456
#define BN (B_*N_)                  // 768
#define EDGE_ELEMS (B_*NN*D_)       // 37748736
#define NODE_ELEMS (BN*D_)          // 98304

typedef short bh8 __attribute__((ext_vector_type(8)));
typedef float f32x4 __attribute__((ext_vector_type(4)));

__device__ __forceinline__ f32x4 mfma_bf16(bh8 a, bh8 b, f32x4 c){
  return __builtin_amdgcn_mfma_f32_16x16x32_bf16(a, b, c, 0, 0, 0);
}
__device__ __forceinline__ unsigned short f2bf(float f){
  unsigned u = __float_as_uint(f);
  return (unsigned short)((u + 0x7fffu + ((u >> 16) & 1u)) >> 16);
}
__device__ __forceinline__ float bf2f(unsigned short h){
  return __uint_as_float(((unsigned)h) << 16);
}
__device__ __forceinline__ float geluf(float x){        // exact (node path only)
  return 0.5f * x * (1.0f + erff(x * 0.70710678118654752f));
}
__device__ __forceinline__ float gelu_fast(float x){    // tanh approx via hw exp
  float x2 = x * x;
  float t  = __fmaf_rn(0.044715f * x, x2, x);           // x + 0.044715 x^3
  float e  = __expf(1.5957691216057308f * t);           // e^{2y}
  float r  = __builtin_amdgcn_rcpf(e + 1.0f);
  return x - x * r;                                     // 0.5x(1+tanh(y))
}
__device__ __forceinline__ f32x4 zero4(){ f32x4 z = {0.f,0.f,0.f,0.f}; return z; }

// ---------------- prep: bf16-transpose the 5 MFMA weights (dst[n][k]) ----------------
__global__ void kprep_w(const float* wqkv_e, const float* e0_we, const float* e0_w1,
                        const float* e1_w1, const float* e1_w2,
                        unsigned short* WqkvT, unsigned short* WeT, unsigned short* W1T,
                        unsigned short* E1W1T, unsigned short* E1W2T){
  int m = blockIdx.y;
  const float* src; unsigned short* dst; int K, Nn;
  if (m == 0){ src = wqkv_e; dst = WqkvT; K = 128; Nn = 512; }
  else if (m == 1){ src = e0_we; dst = WeT;   K = 256; Nn = 128; }
  else if (m == 2){ src = e0_w1; dst = W1T;   K = 128; Nn = 128; }
  else if (m == 3){ src = e1_w1; dst = E1W1T; K = 128; Nn = 256; }
  else            { src = e1_w2; dst = E1W2T; K = 256; Nn = 128; }
  int idx = blockIdx.x * 256 + threadIdx.x;
  if (idx < K * Nn){
    int n = idx / K, k = idx % K;
    dst[idx] = f2bf(src[k * Nn + n]);
  }
}

// ---------------- node qkv: qkvn[b,i,:] = node row @ wqkv_n (fp32) ----------------
__global__ void kqkvn(const float* __restrict__ node, const float* __restrict__ wqkv_n,
                      float* __restrict__ qkvn){
  int row = blockIdx.x;
  int c = threadIdx.x;
  __shared__ float sn[128];
  if (c < 128) sn[c] = node[row * 128 + c];
  __syncthreads();
  float acc = 0.f;
  #pragma unroll 8
  for (int k = 0; k < 128; ++k) acc += sn[k] * wqkv_n[k * 384 + c];
  qkvn[row * 384 + c] = acc;
}

// ---- fused: edge row fp32 -> bf16 (LDS + global E16) + meanJ + flash attention ----
// grid = BN blocks (one (b,i) row), 256 thr. 1 block/CU (LDS 108 KB).
__global__ __launch_bounds__(256, 1) void kattn2(
    const float* __restrict__ edge, const unsigned short* __restrict__ WqkvT,
    const float* __restrict__ qkvn, unsigned short* __restrict__ E16,
    float* __restrict__ meanJ, float* __restrict__ attn){
  __shared__ unsigned short sE[384][136];   // +8 pad: 16B-aligned rows, 2-way banks only
  __shared__ float red[8][128];
  int bi = blockIdx.x; int b = bi / N_, i = bi % N_;
  int tid = threadIdx.x;
  // ---- stage + convert + meanJ partials ----
  const float4* src = (const float4*)(edge + (size_t)bi * N_ * D_);
  ushort4* gdst = (ushort4*)E16 + (size_t)bi * (N_ * D_ / 4);
  float ps0 = 0.f, ps1 = 0.f, ps2 = 0.f, ps3 = 0.f;
  #pragma unroll 4
  for (int k = 0; k < 48; ++k){
    int idx = k * 256 + tid;
    float4 v = src[idx];
    ushort4 o;
    o.x = f2bf(v.x); o.y = f2bf(v.y); o.z = f2bf(v.z); o.w = f2bf(v.w);
    gdst[idx] = o;
    int j = idx >> 5, c4 = idx & 31;
    *(ushort4*)&sE[j][c4 * 4] = o;
    ps0 += v.x; ps1 += v.y; ps2 += v.z; ps3 += v.w;
  }
  { int g = tid >> 5, d0 = (tid & 31) * 4;
    red[g][d0] = ps0; red[g][d0 + 1] = ps1; red[g][d0 + 2] = ps2; red[g][d0 + 3] = ps3; }
  __syncthreads();
  if (tid < 128){
    float s = 0.f;
    #pragma unroll
    for (int g = 0; g < 8; ++g) s += red[g][tid];
    meanJ[bi * 128 + tid] = s * (1.0f / N_);
  }
  // ---- attention (identical math to the passing kattn; A-frags from LDS) ----
  int w = tid >> 6, lane = tid & 63, quad = lane >> 4, c16 = lane & 15;
  const float scale = 0.08838834764831845f;   // 1/sqrt(128)
  for (int s = 0; s < 2; ++s){
    int h = w * 2 + s;
    bh8 bf[4][4];
    #pragma unroll
    for (int u = 0; u < 4; ++u)
      #pragma unroll
      for (int ks = 0; ks < 4; ++ks){
        int col = w * 128 + s * 64 + u * 16 + c16;
        bf[u][ks] = *(const bh8*)(WqkvT + col * 128 + ks * 32 + quad * 8);
      }
    float qv = qkvn[(b * N_ + i) * 384 + h * 48 + c16];
    float m_run = -1e30f, l_run = 0.f, o = 0.f;
    for (int jt = 0; jt < 24; ++jt){
      bh8 af[4];
      #pragma unroll
      for (int ks = 0; ks < 4; ++ks)
        af[ks] = *(const bh8*)&sE[jt * 16 + c16][ks * 32 + quad * 8];
      f32x4 EQ = zero4(), EK = zero4(), EV = zero4(), EM = zero4();
      #pragma unroll
      for (int ks = 0; ks < 4; ++ks){
        EQ = mfma_bf16(af[ks], bf[0][ks], EQ);
        EK = mfma_bf16(af[ks], bf[1][ks], EK);
        EV = mfma_bf16(af[ks], bf[2][ks], EV);
        EM = mfma_bf16(af[ks], bf[3][ks], EM);
      }
      const float* kvb = qkvn + ((size_t)b * N_ + jt * 16 + quad * 4) * 384 + h * 48;
      float dots[4], vv[4];
      #pragma unroll
      for (int r = 0; r < 4; ++r){
        float knv = kvb[r * 384 + 16 + c16];
        float vnv = kvb[r * 384 + 32 + c16];
        float t1 = (qv + EQ[r]) * (knv + EK[r]);
        t1 += __shfl_xor(t1, 1); t1 += __shfl_xor(t1, 2);
        t1 += __shfl_xor(t1, 4); t1 += __shfl_xor(t1, 8);
        dots[r] = t1 * scale;
        vv[r] = vnv * EM[r] + EV[r];
      }
      float tmax = fmaxf(fmaxf(dots[0], dots[1]), fmaxf(dots[2], dots[3]));
      tmax = fmaxf(tmax, __shfl_xor(tmax, 16));
      tmax = fmaxf(tmax, __shfl_xor(tmax, 32));
      float mnew = fmaxf(m_run, tmax);
      float al = __expf(m_run - mnew);
      float p0 = __expf(dots[0] - mnew), p1 = __expf(dots[1] - mnew);
      float p2 = __expf(dots[2] - mnew), p3 = __expf(dots[3] - mnew);
      float lt = p0 + p1 + p2 + p3;
      lt += __shfl_xor(lt, 16); lt += __shfl_xor(lt, 32);
      l_run = l_run * al + lt;
      m_run = mnew;
      o = o * al + p0 * vv[0] + p1 * vv[1] + p2 * vv[2] + p3 * vv[3];
    }
    o += __shfl_xor(o, 16); o += __shfl_xor(o, 32);
    o /= l_run;
    if (quad == 0) attn[(size_t)bi * D_ + h * 16 + c16] = o;
  }
}

// ---------------- meanI over i, reading bf16 E16 ----------------
__global__ void kmeansI(const unsigned short* __restrict__ E16, float* __restrict__ meanI){
  int bj = blockIdx.x; int b = bj / N_, j = bj % N_;
  int d = threadIdx.x;
  const unsigned short* p = E16 + ((size_t)b * NN + j) * D_ + d;
  float s = 0.f;
  #pragma unroll 8
  for (int i = 0; i < N_; ++i) s += bf2f(p[(size_t)i * N_ * D_]);
  meanI[bj * D_ + d] = s * (1.0f / N_);
}

// ---------------- node updates: lin0 + LN0 + MLP + LN1 (fp32) ----------------
__global__ void knode(const float* __restrict__ node, const float* __restrict__ attn,
                      const float* lin0_w, const float* lin0_b,
                      const float* g0, const float* bb0,
                      const float* w1, const float* w2, const float* b2,
                      const float* g1, const float* bb1,
                      float* __restrict__ xOut){
  int row = blockIdx.x; int tid = threadIdx.x;
  __shared__ float sa[128], sx[128], sh[256], rb[8];
  if (tid < 128) sa[tid] = attn[row * 128 + tid];
  __syncthreads();
  float y = 0.f, x0 = 0.f;
  if (tid < 128){
    float acc = lin0_b[tid];
    #pragma unroll 8
    for (int k = 0; k < 128; ++k) acc += sa[k] * lin0_w[k * 128 + tid];
    y = acc + node[row * 128 + tid];
  }
  { float sv = (tid < 128) ? y : 0.f, sq = (tid < 128) ? y * y : 0.f;
    #pragma unroll
    for (int m2 = 32; m2 >= 1; m2 >>= 1){ sv += __shfl_xor(sv, m2); sq += __shfl_xor(sq, m2); }
    if ((tid & 63) == 0){ rb[tid >> 6] = sv; rb[4 + (tid >> 6)] = sq; } }
  __syncthreads();
  float mean = (rb[0] + rb[1] + rb[2] + rb[3]) * (1.f / 128.f);
  float var  = (rb[4] + rb[5] + rb[6] + rb[7]) * (1.f / 128.f) - mean * mean;
  float rstd = rsqrtf(var + 1e-5f);
  if (tid < 128){ x0 = (y - mean) * rstd * g0[tid] + bb0[tid]; sx[tid] = x0; }
  __syncthreads();
  { float acc = 0.f;
    #pragma unroll 8
    for (int k = 0; k < 128; ++k) acc += sx[k] * w1[k * 256 + tid];
    sh[tid] = geluf(acc); }
  __syncthreads();
  float y2 = 0.f;
  if (tid < 128){
    float acc = b2[tid];
    #pragma unroll 8
    for (int e = 0; e < 256; ++e) acc += sh[e] * w2[e * 128 + tid];
    y2 = acc + x0;
  }
  __syncthreads();
  { float sv = (tid < 128) ? y2 : 0.f, sq = (tid < 128) ? y2 * y2 : 0.f;
    #pragma unroll
    for (int m2 = 32; m2 >= 1; m2 >>= 1){ sv += __shfl_xor(sv, m2); sq += __shfl_xor(sq, m2); }
    if ((tid & 63) == 0){ rb[tid >> 6] = sv; rb[4 + (tid >> 6)] = sq; } }
  __syncthreads();
  mean = (rb[0] + rb[1] + rb[2] + rb[3]) * (1.f / 128.f);
  var  = (rb[4] + rb[5] + rb[6] + rb[7]) * (1.f / 128.f) - mean * mean;
  rstd = rsqrtf(var + 1e-5f);
  if (tid < 128) xOut[row * 128 + tid] = (y2 - mean) * rstd * g1[tid] + bb1[tid];
}

// -------- per-row addends: rowAdd = sn+se+be (by i), colAdd = tn+te (by j) --------
__global__ void kaddends(const float* __restrict__ xOut, const float* __restrict__ meanJ,
                         const float* __restrict__ meanI,
                         const float* ws, const float* bs, const float* wt, const float* bt,
                         const float* wer, const float* wec, const float* be,
                         float* __restrict__ rowAdd, float* __restrict__ colAdd){
  int row = blockIdx.x; int d = threadIdx.x;
  __shared__ float sx[128], smJ[128], smI[128];
  sx[d] = xOut[row * 128 + d]; smJ[d] = meanJ[row * 128 + d]; smI[d] = meanI[row * 128 + d];
  __syncthreads();
  float s1 = bs[d], s2 = bt[d], s3 = 0.f, s4 = 0.f;
  #pragma unroll 8
  for (int k = 0; k < 128; ++k){
    s1 += sx[k]  * ws[k * 128 + d];
    s2 += sx[k]  * wt[k * 128 + d];
    s3 += smJ[k] * wer[k * 128 + d];
    s4 += smI[k] * wec[k * 128 + d];
  }
  rowAdd[row * 128 + d] = s1 + s3 + be[d];
  colAdd[row * 128 + d] = s2 + s4;
}

// ------- fused edge pipeline v2: wave-independent 16-row strips, ZERO barriers -------
// Block = 4 waves x 16 rows = 64 rows. LDS 51200 B -> 3 blocks/CU (3 waves/SIMD).
// All LDS regions are wave-private; LN is quad-local shuffle; residuals from bf16 LDS.
__global__ __launch_bounds__(256, 3) void kedge2(
    const unsigned short* __restrict__ E16, const unsigned short* __restrict__ WeT,
    const unsigned short* __restrict__ W1T, const unsigned short* __restrict__ E1W1T,
    const unsigned short* __restrict__ E1W2T,
    const float* __restrict__ rowAdd, const float* __restrict__ colAdd,
    const float* __restrict__ b1, const float* __restrict__ eg0, const float* __restrict__ eb0,
    const float* __restrict__ e1b2, const float* __restrict__ eg1, const float* __restrict__ eb1,
    float* __restrict__ eOut){
  __shared__ unsigned short sA[4][16][264];   // 256-wide edge|edge^T, later edge2 in cols 0..127
  __shared__ unsigned short sT[4][16][136];   // 128-wide C->A transform buffer
  int tid = threadIdx.x;
  int w = tid >> 6, lane = tid & 63, quad = lane >> 4, c16 = lane & 15;
  int R0 = blockIdx.x * 64;
  int b = R0 / NN; int rem = R0 % NN; int i = rem / N_; int j0 = rem % N_;
  int jw = j0 + w * 16;                        // this wave's first j

  // ---- stage 16 rows x 256 cols bf16 (wave-private, no barrier ever) ----
  #pragma unroll
  for (int it = 0; it < 8; ++it){
    int cid = it * 64 + lane;                  // 0..511
    int row = cid >> 5;                        // 0..15
    int kc  = (cid & 31) * 8;                  // 0..248
    const unsigned short* sp;
    if (kc < 128) sp = E16 + ((size_t)(b * N_ + i) * N_ + (jw + row)) * D_ + kc;
    else          sp = E16 + ((size_t)(b * N_ + jw + row) * N_ + i) * D_ + (kc - 128);
    *(float4*)&sA[w][row][kc] = *(const float4*)sp;
  }

  float rAv[8];
  #pragma unroll
  for (int t = 0; t < 8; ++t) rAv[t] = rowAdd[(b * N_ + i) * D_ + t * 16 + c16];

  // ---- G1: (16x256) @ WeT^T -> 16x128, + rowAdd + colAdd, gelu -> sT ----
  #pragma unroll
  for (int th = 0; th < 2; ++th){
    f32x4 a1[4];
    #pragma unroll
    for (int t = 0; t < 4; ++t) a1[t] = zero4();
    #pragma unroll
    for (int ks = 0; ks < 8; ++ks){
      bh8 a = *(const bh8*)&sA[w][c16][ks * 32 + quad * 8];
      #pragma unroll
      for (int t = 0; t < 4; ++t){
        int col = (th * 4 + t) * 16 + c16;
        bh8 bb = *(const bh8*)(WeT + (size_t)col * 256 + ks * 32 + quad * 8);
        a1[t] = mfma_bf16(a, bb, a1[t]);
      }
    }
    #pragma unroll
    for (int t = 0; t < 4; ++t){
      int tt = th * 4 + t; int c = tt * 16 + c16;
      #pragma unroll
      for (int r = 0; r < 4; ++r){
        int m = quad * 4 + r;
        float v = a1[t][r] + rAv[tt] + colAdd[(size_t)(b * N_ + jw + m) * D_ + c];
        sT[w][m][c] = f2bf(gelu_fast(v));
      }
    }
  }

  // ---- G2: gelu1 @ W1T^T + b1 + edge(bf16 residual) -> LN0 -> edge2 (to sA cols 0..127) ----
  f32x4 a2[8];
  #pragma unroll
  for (int t = 0; t < 8; ++t) a2[t] = zero4();
  #pragma unroll
  for (int ks = 0; ks < 4; ++ks){
    bh8 a = *(const bh8*)&sT[w][c16][ks * 32 + quad * 8];
    #pragma unroll
    for (int t = 0; t < 8; ++t){
      bh8 bb = *(const bh8*)(W1T + (size_t)(t * 16 + c16) * 128 + ks * 32 + quad * 8);
      a2[t] = mfma_bf16(a, bb, a2[t]);
    }
  }
  {
    float b1v[8], g0v[8], b0v[8];
    #pragma unroll
    for (int t = 0; t < 8; ++t){
      int c = t * 16 + c16;
      b1v[t] = b1[c]; g0v[t] = eg0[c]; b0v[t] = eb0[c];
    }
    #pragma unroll
    for (int r = 0; r < 4; ++r){
      int m = quad * 4 + r;
      float s = 0.f, q = 0.f;
      #pragma unroll
      for (int t = 0; t < 8; ++t){
        float v = a2[t][r] + b1v[t] + bf2f(sA[w][m][t * 16 + c16]);
        a2[t][r] = v; s += v; q += v * v;
      }
      s += __shfl_xor(s, 1); s += __shfl_xor(s, 2); s += __shfl_xor(s, 4); s += __shfl_xor(s, 8);
      q += __shfl_xor(q, 1); q += __shfl_xor(q, 2); q += __shfl_xor(q, 4); q += __shfl_xor(q, 8);
      float mean = s * (1.f / 128.f);
      float var  = q * (1.f / 128.f) - mean * mean;
      float rstd = rsqrtf(var + 1e-5f);
      #pragma unroll
      for (int t = 0; t < 8; ++t){
        float e2 = (a2[t][r] - mean) * rstd * g0v[t] + b0v[t];
        sA[w][m][t * 16 + c16] = f2bf(e2);
      }
    }
  }

  // ---- G3 (K=128 -> 256 cols, two phases) + gelu -> sT -> G4 (K=256 accumulate) ----
  f32x4 a4[8];
  #pragma unroll
  for (int t = 0; t < 8; ++t) a4[t] = zero4();
  #pragma unroll
  for (int p = 0; p < 2; ++p){
    #pragma unroll
    for (int th = 0; th < 2; ++th){
      f32x4 a3[4];
      #pragma unroll
      for (int t = 0; t < 4; ++t) a3[t] = zero4();
      #pragma unroll
      for (int ks = 0; ks < 4; ++ks){
        bh8 a = *(const bh8*)&sA[w][c16][ks * 32 + quad * 8];
        #pragma unroll
        for (int t = 0; t < 4; ++t){
          int col = p * 128 + (th * 4 + t) * 16 + c16;
          bh8 bb = *(const bh8*)(E1W1T + (size_t)col * 128 + ks * 32 + quad * 8);
          a3[t] = mfma_bf16(a, bb, a3[t]);
        }
      }
      #pragma unroll
      for (int t = 0; t < 4; ++t){
        int c = (th * 4 + t) * 16 + c16;
        #pragma unroll
        for (int r = 0; r < 4; ++r)
          sT[w][quad * 4 + r][c] = f2bf(gelu_fast(a3[t][r]));
      }
    }
    #pragma unroll
    for (int k2 = 0; k2 < 4; ++k2){
      bh8 a = *(const bh8*)&sT[w][c16][k2 * 32 + quad * 8];
      #pragma unroll
      for (int t = 0; t < 8; ++t){
        bh8 bb = *(const bh8*)(E1W2T + (size_t)(t * 16 + c16) * 256 + p * 128 + k2 * 32 + quad * 8);
        a4[t] = mfma_bf16(a, bb, a4[t]);
      }
    }
  }

  // ---- G4 epilogue: + b2 + edge2(bf16) -> LN1 -> store ----
  {
    float b2v[8], g1v[8], bb1v[8];
    #pragma unroll
    for (int t = 0; t < 8; ++t){
      int c = t * 16 + c16;
      b2v[t] = e1b2[c]; g1v[t] = eg1[c]; bb1v[t] = eb1[c];
    }
    #pragma unroll
    for (int r = 0; r < 4; ++r){
      int m = quad * 4 + r;
      float s = 0.f, q = 0.f;
      #pragma unroll
      for (int t = 0; t < 8; ++t){
        float v = a4[t][r] + b2v[t] + bf2f(sA[w][m][t * 16 + c16]);
        a4[t][r] = v; s += v; q += v * v;
      }
      s += __shfl_xor(s, 1); s += __shfl_xor(s, 2); s += __shfl_xor(s, 4); s += __shfl_xor(s, 8);
      q += __shfl_xor(q, 1); q += __shfl_xor(q, 2); q += __shfl_xor(q, 4); q += __shfl_xor(q, 8);
      float mean = s * (1.f / 128.f);
      float var  = q * (1.f / 128.f) - mean * mean;
      float rstd = rsqrtf(var + 1e-5f);
      float* ob = eOut + ((size_t)(b * N_ + i) * N_ + jw + m) * D_;
      #pragma unroll
      for (int t = 0; t < 8; ++t)
        ob[t * 16 + c16] = (a4[t][r] - mean) * rstd * g1v[t] + bb1v[t];
    }
  }
}

extern "C" void kernel_launch(void* const* d_in, const int* in_sizes, int n_in,
                              void* d_out, int out_size, void* d_ws, size_t ws_size,
                              hipStream_t stream){
  const float* node   = (const float*)d_in[0];
  const float* edge   = (const float*)d_in[1];
  const float* wqkv_n = (const float*)d_in[3];
  const float* wqkv_e = (const float*)d_in[4];
  const float* lin0_w = (const float*)d_in[5];
  const float* lin0_b = (const float*)d_in[6];
  const float* ln0_g  = (const float*)d_in[7];
  const float* ln0_b  = (const float*)d_in[8];
  const float* ln1_g  = (const float*)d_in[9];
  const float* ln1_b  = (const float*)d_in[10];
  const float* nmlp_w1= (const float*)d_in[11];
  const float* nmlp_w2= (const float*)d_in[12];
  const float* nmlp_b2= (const float*)d_in[13];
  const float* e0_we  = (const float*)d_in[14];
  const float* e0_be  = (const float*)d_in[15];
  const float* e0_ws  = (const float*)d_in[16];
  const float* e0_bs  = (const float*)d_in[17];
  const float* e0_wt  = (const float*)d_in[18];
  const float* e0_bt  = (const float*)d_in[19];
  const float* e0_wer = (const float*)d_in[20];
  const float* e0_wec = (const float*)d_in[21];
  const float* e0_w1  = (const float*)d_in[22];
  const float* e0_b1  = (const float*)d_in[23];
  const float* e1_w1  = (const float*)d_in[24];
  const float* e1_w2  = (const float*)d_in[25];
  const float* e1_b2  = (const float*)d_in[26];
  const float* eln0_g = (const float*)d_in[27];
  const float* eln0_b = (const float*)d_in[28];
  const float* eln1_g = (const float*)d_in[29];
  const float* eln1_b = (const float*)d_in[30];

  unsigned short* E16   = (unsigned short*)d_ws;
  unsigned short* WqkvT = E16 + (size_t)EDGE_ELEMS;
  unsigned short* WeT   = WqkvT + 65536;
  unsigned short* W1T   = WeT + 32768;
  unsigned short* E1W1T = W1T + 16384;
  unsigned short* E1W2T = E1W1T + 32768;
  float* fbase  = (float*)(E1W2T + 32768);
  float* qkvn   = fbase;
  float* attn   = qkvn + (size_t)BN * 384;
  float* meanJ  = attn + NODE_ELEMS;
  float* meanI  = meanJ + NODE_ELEMS;
  float* rowAdd = meanI + NODE_ELEMS;
  float* colAdd = rowAdd + NODE_ELEMS;

  float* xOut = (float*)d_out;
  float* eOut = xOut + NODE_ELEMS;

  kprep_w<<<dim3(256, 5), 256, 0, stream>>>(wqkv_e, e0_we, e0_w1, e1_w1, e1_w2,
                                            WqkvT, WeT, W1T, E1W1T, E1W2T);
  kqkvn<<<BN, 384, 0, stream>>>(node, wqkv_n, qkvn);
  kattn2<<<BN, 256, 0, stream>>>(edge, WqkvT, qkvn, E16, meanJ, attn);
  kmeansI<<<BN, 128, 0, stream>>>(E16, meanI);
  knode<<<BN, 256, 0, stream>>>(node, attn, lin0_w, lin0_b, ln0_g, ln0_b,
                                nmlp_w1, nmlp_w2, nmlp_b2, ln1_g, ln1_b, xOut);
  kaddends<<<BN, 128, 0, stream>>>(xOut, meanJ, meanI, e0_ws, e0_bs, e0_wt, e0_bt,
                                   e0_wer, e0_wec, e0_be, rowAdd, colAdd);
  kedge2<<<NN * B_ / 64, 256, 0, stream>>>(E16, WeT, W1T, E1W1T, E1W2T,
                                           rowAdd, colAdd, e0_b1,
                                           eln0_g, eln0_b, e1_b2, eln1_g, eln1_b,
                                           eOut);
}

// Round 3
// 785.026 us; speedup vs baseline: 1.4266x; 1.4266x over previous
//
#include <hip/hip_runtime.h>
#include <cstdint>
#include <cstddef>

#define B_ 2
#define N_ 384
#define D_ 128
#define NN (N_*N_)                  // 147456
#define BN (B_*N_)                  // 768
#define EDGE_ELEMS (B_*NN*D_)       // 37748736
#define NODE_ELEMS (BN*D_)          // 98304

typedef short bh8 __attribute__((ext_vector_type(8)));
typedef float f32x4 __attribute__((ext_vector_type(4)));

__device__ __forceinline__ f32x4 mfma_bf16(bh8 a, bh8 b, f32x4 c){
  return __builtin_amdgcn_mfma_f32_16x16x32_bf16(a, b, c, 0, 0, 0);
}
__device__ __forceinline__ unsigned short f2bf(float f){
  unsigned u = __float_as_uint(f);
  return (unsigned short)((u + 0x7fffu + ((u >> 16) & 1u)) >> 16);
}
__device__ __forceinline__ float bf2f(unsigned short h){
  return __uint_as_float(((unsigned)h) << 16);
}
__device__ __forceinline__ float geluf(float x){        // exact (node path)
  return 0.5f * x * (1.0f + erff(x * 0.70710678118654752f));
}
__device__ __forceinline__ float gelu_fast(float x){    // tanh approx via hw exp
  float x2 = x * x;
  float t  = __fmaf_rn(0.044715f * x, x2, x);
  float e  = __expf(1.5957691216057308f * t);
  float r  = __builtin_amdgcn_rcpf(e + 1.0f);
  return x - x * r;
}
__device__ __forceinline__ f32x4 zero4(){ f32x4 z = {0.f,0.f,0.f,0.f}; return z; }

// ---------------- prep: bf16-transpose the 5 MFMA weights (dst[n][k]) ----------------
__global__ void kprep_w(const float* wqkv_e, const float* e0_we, const float* e0_w1,
                        const float* e1_w1, const float* e1_w2,
                        unsigned short* WqkvT, unsigned short* WeT, unsigned short* W1T,
                        unsigned short* E1W1T, unsigned short* E1W2T){
  int m = blockIdx.y;
  const float* src; unsigned short* dst; int K, Nn;
  if (m == 0){ src = wqkv_e; dst = WqkvT; K = 128; Nn = 512; }
  else if (m == 1){ src = e0_we; dst = WeT;   K = 256; Nn = 128; }
  else if (m == 2){ src = e0_w1; dst = W1T;   K = 128; Nn = 128; }
  else if (m == 3){ src = e1_w1; dst = E1W1T; K = 128; Nn = 256; }
  else            { src = e1_w2; dst = E1W2T; K = 256; Nn = 128; }
  int idx = blockIdx.x * 256 + threadIdx.x;
  if (idx < K * Nn){
    int n = idx / K, k = idx % K;
    dst[idx] = f2bf(src[k * Nn + n]);
  }
}

// ---------------- fused: edge fp32 -> bf16 + meanJ (contiguous row pass) ----------------
__global__ void kprepA(const float* __restrict__ edge, unsigned short* __restrict__ E16,
                       float* __restrict__ meanJ){
  __shared__ float red[8][128];
  int bi = blockIdx.x; int tid = threadIdx.x;
  const float4* src = (const float4*)(edge + (size_t)bi * N_ * D_);
  ushort4* gdst = (ushort4*)E16 + (size_t)bi * (N_ * D_ / 4);
  float ps0 = 0.f, ps1 = 0.f, ps2 = 0.f, ps3 = 0.f;
  #pragma unroll 4
  for (int k = 0; k < 48; ++k){
    int idx = k * 256 + tid;
    float4 v = src[idx];
    ushort4 o;
    o.x = f2bf(v.x); o.y = f2bf(v.y); o.z = f2bf(v.z); o.w = f2bf(v.w);
    gdst[idx] = o;
    ps0 += v.x; ps1 += v.y; ps2 += v.z; ps3 += v.w;
  }
  int g = tid >> 5, d0 = (tid & 31) * 4;
  red[g][d0] = ps0; red[g][d0 + 1] = ps1; red[g][d0 + 2] = ps2; red[g][d0 + 3] = ps3;
  __syncthreads();
  if (tid < 128){
    float s = 0.f;
    #pragma unroll
    for (int gg = 0; gg < 8; ++gg) s += red[gg][tid];
    meanJ[bi * 128 + tid] = s * (1.0f / N_);
  }
}

// ---------------- meanI over i, vectorized 16B loads from E16 ----------------
__global__ void kmeansI2(const unsigned short* __restrict__ E16, float* __restrict__ meanI){
  __shared__ float red[16][128];
  int bj = blockIdx.x; int b = bj / N_, j = bj % N_;
  int tid = threadIdx.x;
  int ig = tid >> 4, dsub = tid & 15;          // 16 i-groups x 16 d-chunks
  float acc[8];
  #pragma unroll
  for (int e = 0; e < 8; ++e) acc[e] = 0.f;
  #pragma unroll 4
  for (int i = ig; i < N_; i += 16){
    const unsigned short* p = E16 + ((size_t)(b * N_ + i) * N_ + j) * D_ + dsub * 8;
    uint4 u = *(const uint4*)p;
    acc[0] += bf2f((unsigned short)(u.x & 0xffff)); acc[1] += bf2f((unsigned short)(u.x >> 16));
    acc[2] += bf2f((unsigned short)(u.y & 0xffff)); acc[3] += bf2f((unsigned short)(u.y >> 16));
    acc[4] += bf2f((unsigned short)(u.z & 0xffff)); acc[5] += bf2f((unsigned short)(u.z >> 16));
    acc[6] += bf2f((unsigned short)(u.w & 0xffff)); acc[7] += bf2f((unsigned short)(u.w >> 16));
  }
  #pragma unroll
  for (int e = 0; e < 8; ++e) red[ig][dsub * 8 + e] = acc[e];
  __syncthreads();
  if (tid < 128){
    float s = 0.f;
    #pragma unroll
    for (int gg = 0; gg < 16; ++gg) s += red[gg][tid];
    meanI[bj * 128 + tid] = s * (1.0f / N_);
  }
}

// ---------------- node qkv: qkvn[b,i,:] = node row @ wqkv_n (fp32) ----------------
__global__ void kqkvn(const float* __restrict__ node, const float* __restrict__ wqkv_n,
                      float* __restrict__ qkvn){
  int row = blockIdx.x;
  int c = threadIdx.x;
  __shared__ float sn[128];
  if (c < 128) sn[c] = node[row * 128 + c];
  __syncthreads();
  float acc = 0.f;
  #pragma unroll 8
  for (int k = 0; k < 128; ++k) acc += sn[k] * wqkv_n[k * 384 + c];
  qkvn[row * 384 + c] = acc;
}

// ---- attention v3: wave w computes heads {w, w+4}, shared A-frags + prefetch ----
__global__ __launch_bounds__(256, 2) void kattn3(
    const unsigned short* __restrict__ E16, const unsigned short* __restrict__ WqkvT,
    const float* __restrict__ qkvn, float* __restrict__ attn){
  int bi = blockIdx.x; int b = bi / N_;
  int tid = threadIdx.x;
  int w = tid >> 6, lane = tid & 63, quad = lane >> 4, c16 = lane & 15;
  const float scale = 0.08838834764831845f;   // 1/sqrt(128)
  const unsigned short* Abase = E16 + (size_t)bi * N_ * D_;

  bh8 bf[2][4][4];
  #pragma unroll
  for (int s = 0; s < 2; ++s){
    int h = w + s * 4;
    #pragma unroll
    for (int u = 0; u < 4; ++u)
      #pragma unroll
      for (int ks = 0; ks < 4; ++ks){
        int col = h * 64 + u * 16 + c16;
        bf[s][u][ks] = *(const bh8*)(WqkvT + col * 128 + ks * 32 + quad * 8);
      }
  }
  float qv[2];
  #pragma unroll
  for (int s = 0; s < 2; ++s) qv[s] = qkvn[bi * 384 + (w + s * 4) * 48 + c16];

  float m_run[2] = {-1e30f, -1e30f}, l_run[2] = {0.f, 0.f}, o[2] = {0.f, 0.f};
  bh8 af[4];
  #pragma unroll
  for (int ks = 0; ks < 4; ++ks)
    af[ks] = *(const bh8*)(Abase + (size_t)c16 * D_ + ks * 32 + quad * 8);

  for (int jt = 0; jt < 24; ++jt){
    int jn = (jt + 1 < 24) ? jt + 1 : 0;
    bh8 afn[4];
    #pragma unroll
    for (int ks = 0; ks < 4; ++ks)
      afn[ks] = *(const bh8*)(Abase + (size_t)(jn * 16 + c16) * D_ + ks * 32 + quad * 8);
    float knv[2][4], vnv[2][4];
    const float* kvb = qkvn + ((size_t)b * N_ + jt * 16 + quad * 4) * 384;
    #pragma unroll
    for (int s = 0; s < 2; ++s)
      #pragma unroll
      for (int r = 0; r < 4; ++r){
        knv[s][r] = kvb[r * 384 + (w + s * 4) * 48 + 16 + c16];
        vnv[s][r] = kvb[r * 384 + (w + s * 4) * 48 + 32 + c16];
      }
    f32x4 EQ[2], EK[2], EV[2], EM[2];
    #pragma unroll
    for (int s = 0; s < 2; ++s){ EQ[s] = zero4(); EK[s] = zero4(); EV[s] = zero4(); EM[s] = zero4(); }
    #pragma unroll
    for (int ks = 0; ks < 4; ++ks)
      #pragma unroll
      for (int s = 0; s < 2; ++s){
        EQ[s] = mfma_bf16(af[ks], bf[s][0][ks], EQ[s]);
        EK[s] = mfma_bf16(af[ks], bf[s][1][ks], EK[s]);
        EV[s] = mfma_bf16(af[ks], bf[s][2][ks], EV[s]);
        EM[s] = mfma_bf16(af[ks], bf[s][3][ks], EM[s]);
      }
    #pragma unroll
    for (int s = 0; s < 2; ++s){
      float dots[4], vv[4];
      #pragma unroll
      for (int r = 0; r < 4; ++r){
        float t1 = (qv[s] + EQ[s][r]) * (knv[s][r] + EK[s][r]);
        t1 += __shfl_xor(t1, 1); t1 += __shfl_xor(t1, 2);
        t1 += __shfl_xor(t1, 4); t1 += __shfl_xor(t1, 8);
        dots[r] = t1 * scale;
        vv[r] = vnv[s][r] * EM[s][r] + EV[s][r];
      }
      float tmax = fmaxf(fmaxf(dots[0], dots[1]), fmaxf(dots[2], dots[3]));
      tmax = fmaxf(tmax, __shfl_xor(tmax, 16));
      tmax = fmaxf(tmax, __shfl_xor(tmax, 32));
      float mnew = fmaxf(m_run[s], tmax);
      float al = __expf(m_run[s] - mnew);
      float p0 = __expf(dots[0] - mnew), p1 = __expf(dots[1] - mnew);
      float p2 = __expf(dots[2] - mnew), p3 = __expf(dots[3] - mnew);
      float lt = p0 + p1 + p2 + p3;
      lt += __shfl_xor(lt, 16); lt += __shfl_xor(lt, 32);
      l_run[s] = l_run[s] * al + lt;
      m_run[s] = mnew;
      o[s] = o[s] * al + p0 * vv[0] + p1 * vv[1] + p2 * vv[2] + p3 * vv[3];
    }
    #pragma unroll
    for (int ks = 0; ks < 4; ++ks) af[ks] = afn[ks];
  }
  #pragma unroll
  for (int s = 0; s < 2; ++s){
    float oo = o[s];
    oo += __shfl_xor(oo, 16); oo += __shfl_xor(oo, 32);
    oo /= l_run[s];
    if (quad == 0) attn[(size_t)bi * D_ + (w + s * 4) * 16 + c16] = oo;
  }
}

// ---------------- node updates: lin0 + LN0 + MLP + LN1 (fp32) ----------------
__global__ void knode(const float* __restrict__ node, const float* __restrict__ attn,
                      const float* lin0_w, const float* lin0_b,
                      const float* g0, const float* bb0,
                      const float* w1, const float* w2, const float* b2,
                      const float* g1, const float* bb1,
                      float* __restrict__ xOut){
  int row = blockIdx.x; int tid = threadIdx.x;
  __shared__ float sa[128], sx[128], sh[256], rb[8];
  if (tid < 128) sa[tid] = attn[row * 128 + tid];
  __syncthreads();
  float y = 0.f, x0 = 0.f;
  if (tid < 128){
    float acc = lin0_b[tid];
    #pragma unroll 8
    for (int k = 0; k < 128; ++k) acc += sa[k] * lin0_w[k * 128 + tid];
    y = acc + node[row * 128 + tid];
  }
  { float sv = (tid < 128) ? y : 0.f, sq = (tid < 128) ? y * y : 0.f;
    #pragma unroll
    for (int m2 = 32; m2 >= 1; m2 >>= 1){ sv += __shfl_xor(sv, m2); sq += __shfl_xor(sq, m2); }
    if ((tid & 63) == 0){ rb[tid >> 6] = sv; rb[4 + (tid >> 6)] = sq; } }
  __syncthreads();
  float mean = (rb[0] + rb[1] + rb[2] + rb[3]) * (1.f / 128.f);
  float var  = (rb[4] + rb[5] + rb[6] + rb[7]) * (1.f / 128.f) - mean * mean;
  float rstd = rsqrtf(var + 1e-5f);
  if (tid < 128){ x0 = (y - mean) * rstd * g0[tid] + bb0[tid]; sx[tid] = x0; }
  __syncthreads();
  { float acc = 0.f;
    #pragma unroll 8
    for (int k = 0; k < 128; ++k) acc += sx[k] * w1[k * 256 + tid];
    sh[tid] = geluf(acc); }
  __syncthreads();
  float y2 = 0.f;
  if (tid < 128){
    float acc = b2[tid];
    #pragma unroll 8
    for (int e = 0; e < 256; ++e) acc += sh[e] * w2[e * 128 + tid];
    y2 = acc + x0;
  }
  __syncthreads();
  { float sv = (tid < 128) ? y2 : 0.f, sq = (tid < 128) ? y2 * y2 : 0.f;
    #pragma unroll
    for (int m2 = 32; m2 >= 1; m2 >>= 1){ sv += __shfl_xor(sv, m2); sq += __shfl_xor(sq, m2); }
    if ((tid & 63) == 0){ rb[tid >> 6] = sv; rb[4 + (tid >> 6)] = sq; } }
  __syncthreads();
  mean = (rb[0] + rb[1] + rb[2] + rb[3]) * (1.f / 128.f);
  var  = (rb[4] + rb[5] + rb[6] + rb[7]) * (1.f / 128.f) - mean * mean;
  rstd = rsqrtf(var + 1e-5f);
  if (tid < 128) xOut[row * 128 + tid] = (y2 - mean) * rstd * g1[tid] + bb1[tid];
}

// -------- per-row addends: rowAdd = sn+se+be (by i), colAdd = tn+te (by j) --------
__global__ void kaddends(const float* __restrict__ xOut, const float* __restrict__ meanJ,
                         const float* __restrict__ meanI,
                         const float* ws, const float* bs, const float* wt, const float* bt,
                         const float* wer, const float* wec, const float* be,
                         float* __restrict__ rowAdd, float* __restrict__ colAdd){
  int row = blockIdx.x; int d = threadIdx.x;
  __shared__ float sx[128], smJ[128], smI[128];
  sx[d] = xOut[row * 128 + d]; smJ[d] = meanJ[row * 128 + d]; smI[d] = meanI[row * 128 + d];
  __syncthreads();
  float s1 = bs[d], s2 = bt[d], s3 = 0.f, s4 = 0.f;
  #pragma unroll 8
  for (int k = 0; k < 128; ++k){
    s1 += sx[k]  * ws[k * 128 + d];
    s2 += sx[k]  * wt[k * 128 + d];
    s3 += smJ[k] * wer[k * 128 + d];
    s4 += smI[k] * wec[k * 128 + d];
  }
  rowAdd[row * 128 + d] = s1 + s3 + be[d];
  colAdd[row * 128 + d] = s2 + s4;
}

// -- fused edge pipeline v3: col-split waves + register-hoisted weight prefetch --
// 64-row tiles, 4 waves; wave w owns cols [32w,32w+32) (G3: [64w,64w+64)).
// LDS 69.6 KB -> 2 blocks/CU; launch_bounds(256,2) allows up to 256 VGPRs.
__global__ __launch_bounds__(256, 2) void kedge3(
    const unsigned short* __restrict__ E16, const unsigned short* __restrict__ WeT,
    const unsigned short* __restrict__ W1T, const unsigned short* __restrict__ E1W1T,
    const unsigned short* __restrict__ E1W2T,
    const float* __restrict__ rowAdd, const float* __restrict__ colAdd,
    const float* __restrict__ b1, const float* __restrict__ eg0, const float* __restrict__ eb0,
    const float* __restrict__ e1b2, const float* __restrict__ eg1, const float* __restrict__ eb1,
    float* __restrict__ eOut){
  __shared__ unsigned short sA[64][264];   // edge|edgeT; cols 0..127 become edge2 after LN0
  __shared__ unsigned short sT[64][264];   // stage-to-stage activation buffer (max 256 wide)
  __shared__ float lrS[4][64], lrQ[4][64];
  int tid = threadIdx.x;
  int w = tid >> 6, lane = tid & 63, quad = lane >> 4, c16 = lane & 15;
  int R0 = blockIdx.x * 64;
  int b = R0 / NN; int rem = R0 % NN; int i = rem / N_; int j0 = rem % N_;

  // ---- prefetch G1 weights (issued before staging so everything overlaps) ----
  bh8 wb1[2][8];
  #pragma unroll
  for (int t = 0; t < 2; ++t)
    #pragma unroll
    for (int ks = 0; ks < 8; ++ks){
      int col = w * 32 + t * 16 + c16;
      wb1[t][ks] = *(const bh8*)(WeT + (size_t)col * 256 + ks * 32 + quad * 8);
    }
  // ---- prefetch colAdd / rowAdd for the G1 epilogue ----
  float ca[2][16], rAv[2];
  #pragma unroll
  for (int t = 0; t < 2; ++t){
    rAv[t] = rowAdd[(b * N_ + i) * D_ + w * 32 + t * 16 + c16];
    #pragma unroll
    for (int ms = 0; ms < 4; ++ms)
      #pragma unroll
      for (int r = 0; r < 4; ++r)
        ca[t][ms * 4 + r] = colAdd[(size_t)(b * N_ + j0 + ms * 16 + quad * 4 + r) * D_
                                   + w * 32 + t * 16 + c16];
  }

  // ---- stage A = [edge(b,i,j0+m,:) | edge(b,j0+m,i,:)] bf16, 64x256 ----
  #pragma unroll
  for (int it = 0; it < 8; ++it){
    int cid = it * 256 + tid;
    int rrow = cid >> 5;
    int kc = (cid & 31) * 8;
    const unsigned short* sp;
    if (kc < 128) sp = E16 + ((size_t)(b * N_ + i) * N_ + (j0 + rrow)) * D_ + kc;
    else          sp = E16 + ((size_t)(b * N_ + j0 + rrow) * N_ + i) * D_ + (kc - 128);
    *(float4*)&sA[rrow][kc] = *(const float4*)sp;
  }
  __syncthreads();

  // ---- G1: A(64x256) @ WeT^T -> cols [32w,32w+32); epi: +rowAdd+colAdd, gelu -> sT ----
  f32x4 acc1[2][4];
  #pragma unroll
  for (int t = 0; t < 2; ++t) for (int ms = 0; ms < 4; ++ms) acc1[t][ms] = zero4();
  #pragma unroll
  for (int ks = 0; ks < 8; ++ks){
    bh8 af[4];
    #pragma unroll
    for (int ms = 0; ms < 4; ++ms)
      af[ms] = *(const bh8*)&sA[ms * 16 + c16][ks * 32 + quad * 8];
    #pragma unroll
    for (int t = 0; t < 2; ++t)
      #pragma unroll
      for (int ms = 0; ms < 4; ++ms)
        acc1[t][ms] = mfma_bf16(af[ms], wb1[t][ks], acc1[t][ms]);
  }
  #pragma unroll
  for (int t = 0; t < 2; ++t)
    #pragma unroll
    for (int ms = 0; ms < 4; ++ms)
      #pragma unroll
      for (int r = 0; r < 4; ++r){
        int m = ms * 16 + quad * 4 + r;
        float v = acc1[t][ms][r] + rAv[t] + ca[t][ms * 4 + r];
        sT[m][w * 32 + t * 16 + c16] = f2bf(gelu_fast(v));
      }
  __syncthreads();

  // ---- G2: gelu1 @ W1T^T + b1 + edge(bf16, sA) -> LN0 partials ----
  bh8 wb2[2][4];
  #pragma unroll
  for (int t = 0; t < 2; ++t)
    #pragma unroll
    for (int ks = 0; ks < 4; ++ks){
      int col = w * 32 + t * 16 + c16;
      wb2[t][ks] = *(const bh8*)(W1T + (size_t)col * 128 + ks * 32 + quad * 8);
    }
  f32x4 acc2[2][4];
  #pragma unroll
  for (int t = 0; t < 2; ++t) for (int ms = 0; ms < 4; ++ms) acc2[t][ms] = zero4();
  #pragma unroll
  for (int ks = 0; ks < 4; ++ks){
    bh8 af[4];
    #pragma unroll
    for (int ms = 0; ms < 4; ++ms)
      af[ms] = *(const bh8*)&sT[ms * 16 + c16][ks * 32 + quad * 8];
    #pragma unroll
    for (int t = 0; t < 2; ++t)
      #pragma unroll
      for (int ms = 0; ms < 4; ++ms)
        acc2[t][ms] = mfma_bf16(af[ms], wb2[t][ks], acc2[t][ms]);
  }
  float b1v[2], g0v[2], b0v[2];
  #pragma unroll
  for (int t = 0; t < 2; ++t){
    int c = w * 32 + t * 16 + c16;
    b1v[t] = b1[c]; g0v[t] = eg0[c]; b0v[t] = eb0[c];
  }
  #pragma unroll
  for (int ms = 0; ms < 4; ++ms)
    #pragma unroll
    for (int r = 0; r < 4; ++r){
      int m = ms * 16 + quad * 4 + r;
      float s = 0.f, q = 0.f;
      #pragma unroll
      for (int t = 0; t < 2; ++t){
        float v = acc2[t][ms][r] + b1v[t] + bf2f(sA[m][w * 32 + t * 16 + c16]);
        acc2[t][ms][r] = v; s += v; q += v * v;
      }
      s += __shfl_xor(s, 1); s += __shfl_xor(s, 2); s += __shfl_xor(s, 4); s += __shfl_xor(s, 8);
      q += __shfl_xor(q, 1); q += __shfl_xor(q, 2); q += __shfl_xor(q, 4); q += __shfl_xor(q, 8);
      if (c16 == 0){ lrS[w][m] = s; lrQ[w][m] = q; }
    }
  __syncthreads();

  // ---- LN0 finalize -> edge2 bf16 into sA cols 0..127 ----
  #pragma unroll
  for (int ms = 0; ms < 4; ++ms)
    #pragma unroll
    for (int r = 0; r < 4; ++r){
      int m = ms * 16 + quad * 4 + r;
      float s = lrS[0][m] + lrS[1][m] + lrS[2][m] + lrS[3][m];
      float q = lrQ[0][m] + lrQ[1][m] + lrQ[2][m] + lrQ[3][m];
      float mean = s * (1.f / 128.f);
      float var  = q * (1.f / 128.f) - mean * mean;
      float rstd = rsqrtf(var + 1e-5f);
      #pragma unroll
      for (int t = 0; t < 2; ++t){
        float e2 = (acc2[t][ms][r] - mean) * rstd * g0v[t] + b0v[t];
        sA[m][w * 32 + t * 16 + c16] = f2bf(e2);
      }
    }
  __syncthreads();

  // ---- G3: edge2 @ E1W1T^T -> cols [64w,64w+64); gelu -> sT (256 wide) ----
  bh8 wb3[4][4];
  #pragma unroll
  for (int t = 0; t < 4; ++t)
    #pragma unroll
    for (int ks = 0; ks < 4; ++ks){
      int col = w * 64 + t * 16 + c16;
      wb3[t][ks] = *(const bh8*)(E1W1T + (size_t)col * 128 + ks * 32 + quad * 8);
    }
  f32x4 acc3[4][4];
  #pragma unroll
  for (int t = 0; t < 4; ++t) for (int ms = 0; ms < 4; ++ms) acc3[t][ms] = zero4();
  #pragma unroll
  for (int ks = 0; ks < 4; ++ks){
    bh8 af[4];
    #pragma unroll
    for (int ms = 0; ms < 4; ++ms)
      af[ms] = *(const bh8*)&sA[ms * 16 + c16][ks * 32 + quad * 8];
    #pragma unroll
    for (int t = 0; t < 4; ++t)
      #pragma unroll
      for (int ms = 0; ms < 4; ++ms)
        acc3[t][ms] = mfma_bf16(af[ms], wb3[t][ks], acc3[t][ms]);
  }
  #pragma unroll
  for (int t = 0; t < 4; ++t)
    #pragma unroll
    for (int ms = 0; ms < 4; ++ms)
      #pragma unroll
      for (int r = 0; r < 4; ++r){
        int m = ms * 16 + quad * 4 + r;
        sT[m][w * 64 + t * 16 + c16] = f2bf(gelu_fast(acc3[t][ms][r]));
      }
  __syncthreads();

  // ---- G4: gelu3 @ E1W2T^T + b2 + edge2 -> LN1 -> store ----
  bh8 wb4[2][8];
  #pragma unroll
  for (int t = 0; t < 2; ++t)
    #pragma unroll
    for (int ks = 0; ks < 8; ++ks){
      int col = w * 32 + t * 16 + c16;
      wb4[t][ks] = *(const bh8*)(E1W2T + (size_t)col * 256 + ks * 32 + quad * 8);
    }
  f32x4 acc4[2][4];
  #pragma unroll
  for (int t = 0; t < 2; ++t) for (int ms = 0; ms < 4; ++ms) acc4[t][ms] = zero4();
  #pragma unroll
  for (int ks = 0; ks < 8; ++ks){
    bh8 af[4];
    #pragma unroll
    for (int ms = 0; ms < 4; ++ms)
      af[ms] = *(const bh8*)&sT[ms * 16 + c16][ks * 32 + quad * 8];
    #pragma unroll
    for (int t = 0; t < 2; ++t)
      #pragma unroll
      for (int ms = 0; ms < 4; ++ms)
        acc4[t][ms] = mfma_bf16(af[ms], wb4[t][ks], acc4[t][ms]);
  }
  float b2v[2], g1v[2], bb1v[2];
  #pragma unroll
  for (int t = 0; t < 2; ++t){
    int c = w * 32 + t * 16 + c16;
    b2v[t] = e1b2[c]; g1v[t] = eg1[c]; bb1v[t] = eb1[c];
  }
  #pragma unroll
  for (int ms = 0; ms < 4; ++ms)
    #pragma unroll
    for (int r = 0; r < 4; ++r){
      int m = ms * 16 + quad * 4 + r;
      float s = 0.f, q = 0.f;
      #pragma unroll
      for (int t = 0; t < 2; ++t){
        float v = acc4[t][ms][r] + b2v[t] + bf2f(sA[m][w * 32 + t * 16 + c16]);
        acc4[t][ms][r] = v; s += v; q += v * v;
      }
      s += __shfl_xor(s, 1); s += __shfl_xor(s, 2); s += __shfl_xor(s, 4); s += __shfl_xor(s, 8);
      q += __shfl_xor(q, 1); q += __shfl_xor(q, 2); q += __shfl_xor(q, 4); q += __shfl_xor(q, 8);
      if (c16 == 0){ lrS[w][m] = s; lrQ[w][m] = q; }
    }
  __syncthreads();
  float* outBase = eOut + ((size_t)(b * N_ + i) * N_ + j0) * D_;
  #pragma unroll
  for (int ms = 0; ms < 4; ++ms)
    #pragma unroll
    for (int r = 0; r < 4; ++r){
      int m = ms * 16 + quad * 4 + r;
      float s = lrS[0][m] + lrS[1][m] + lrS[2][m] + lrS[3][m];
      float q = lrQ[0][m] + lrQ[1][m] + lrQ[2][m] + lrQ[3][m];
      float mean = s * (1.f / 128.f);
      float var  = q * (1.f / 128.f) - mean * mean;
      float rstd = rsqrtf(var + 1e-5f);
      #pragma unroll
      for (int t = 0; t < 2; ++t){
        int c = w * 32 + t * 16 + c16;
        outBase[(size_t)m * D_ + c] = (acc4[t][ms][r] - mean) * rstd * g1v[t] + bb1v[t];
      }
    }
}

extern "C" void kernel_launch(void* const* d_in, const int* in_sizes, int n_in,
                              void* d_out, int out_size, void* d_ws, size_t ws_size,
                              hipStream_t stream){
  const float* node   = (const float*)d_in[0];
  const float* edge   = (const float*)d_in[1];
  const float* wqkv_n = (const float*)d_in[3];
  const float* wqkv_e = (const float*)d_in[4];
  const float* lin0_w = (const float*)d_in[5];
  const float* lin0_b = (const float*)d_in[6];
  const float* ln0_g  = (const float*)d_in[7];
  const float* ln0_b  = (const float*)d_in[8];
  const float* ln1_g  = (const float*)d_in[9];
  const float* ln1_b  = (const float*)d_in[10];
  const float* nmlp_w1= (const float*)d_in[11];
  const float* nmlp_w2= (const float*)d_in[12];
  const float* nmlp_b2= (const float*)d_in[13];
  const float* e0_we  = (const float*)d_in[14];
  const float* e0_be  = (const float*)d_in[15];
  const float* e0_ws  = (const float*)d_in[16];
  const float* e0_bs  = (const float*)d_in[17];
  const float* e0_wt  = (const float*)d_in[18];
  const float* e0_bt  = (const float*)d_in[19];
  const float* e0_wer = (const float*)d_in[20];
  const float* e0_wec = (const float*)d_in[21];
  const float* e0_w1  = (const float*)d_in[22];
  const float* e0_b1  = (const float*)d_in[23];
  const float* e1_w1  = (const float*)d_in[24];
  const float* e1_w2  = (const float*)d_in[25];
  const float* e1_b2  = (const float*)d_in[26];
  const float* eln0_g = (const float*)d_in[27];
  const float* eln0_b = (const float*)d_in[28];
  const float* eln1_g = (const float*)d_in[29];
  const float* eln1_b = (const float*)d_in[30];

  unsigned short* E16   = (unsigned short*)d_ws;
  unsigned short* WqkvT = E16 + (size_t)EDGE_ELEMS;
  unsigned short* WeT   = WqkvT + 65536;
  unsigned short* W1T   = WeT + 32768;
  unsigned short* E1W1T = W1T + 16384;
  unsigned short* E1W2T = E1W1T + 32768;
  float* fbase  = (float*)(E1W2T + 32768);
  float* qkvn   = fbase;
  float* attn   = qkvn + (size_t)BN * 384;
  float* meanJ  = attn + NODE_ELEMS;
  float* meanI  = meanJ + NODE_ELEMS;
  float* rowAdd = meanI + NODE_ELEMS;
  float* colAdd = rowAdd + NODE_ELEMS;

  float* xOut = (float*)d_out;
  float* eOut = xOut + NODE_ELEMS;

  kprep_w<<<dim3(256, 5), 256, 0, stream>>>(wqkv_e, e0_we, e0_w1, e1_w1, e1_w2,
                                            WqkvT, WeT, W1T, E1W1T, E1W2T);
  kprepA<<<BN, 256, 0, stream>>>(edge, E16, meanJ);
  kqkvn<<<BN, 384, 0, stream>>>(node, wqkv_n, qkvn);
  kmeansI2<<<BN, 256, 0, stream>>>(E16, meanI);
  kattn3<<<BN, 256, 0, stream>>>(E16, WqkvT, qkvn, attn);
  knode<<<BN, 256, 0, stream>>>(node, attn, lin0_w, lin0_b, ln0_g, ln0_b,
                                nmlp_w1, nmlp_w2, nmlp_b2, ln1_g, ln1_b, xOut);
  kaddends<<<BN, 128, 0, stream>>>(xOut, meanJ, meanI, e0_ws, e0_bs, e0_wt, e0_bt,
                                   e0_wer, e0_wec, e0_be, rowAdd, colAdd);
  kedge3<<<NN * B_ / 64, 256, 0, stream>>>(E16, WeT, W1T, E1W1T, E1W2T,
                                           rowAdd, colAdd, e0_b1,
                                           eln0_g, eln0_b, e1_b2, eln1_g, eln1_b,
                                           eOut);
}

// Round 4
// 637.429 us; speedup vs baseline: 1.7570x; 1.2316x over previous
//
#include <hip/hip_runtime.h>
#include <hip/hip_bf16.h>
#include <cstdint>
#include <cstddef>

#define B_ 2
#define N_ 384
#define D_ 128
#define NN (N_*N_)                  // 147456
#define BN (B_*N_)                  // 768
#define EDGE_ELEMS (B_*NN*D_)       // 37748736
#define NODE_ELEMS (BN*D_)          // 98304

typedef short bh8 __attribute__((ext_vector_type(8)));
typedef float f32x4 __attribute__((ext_vector_type(4)));

__device__ __forceinline__ f32x4 mfma_bf16(bh8 a, bh8 b, f32x4 c){
  return __builtin_amdgcn_mfma_f32_16x16x32_bf16(a, b, c, 0, 0, 0);
}
__device__ __forceinline__ unsigned short f2bf(float f){
  unsigned u = __float_as_uint(f);
  return (unsigned short)((u + 0x7fffu + ((u >> 16) & 1u)) >> 16);
}
__device__ __forceinline__ unsigned f2bf_pk(float a, float b){   // packed cvt: lo=a, hi=b
  __hip_bfloat162 h = __float22bfloat162_rn(make_float2(a, b));
  return *(unsigned*)&h;
}
__device__ __forceinline__ float bf2f(unsigned short h){
  return __uint_as_float(((unsigned)h) << 16);
}
__device__ __forceinline__ float geluf(float x){        // exact (node path)
  return 0.5f * x * (1.0f + erff(x * 0.70710678118654752f));
}
__device__ __forceinline__ float gelu_fast(float x){    // tanh approx via hw exp
  float x2 = x * x;
  float t  = __fmaf_rn(0.044715f * x, x2, x);
  float e  = __expf(1.5957691216057308f * t);
  float r  = __builtin_amdgcn_rcpf(e + 1.0f);
  return x - x * r;
}
__device__ __forceinline__ f32x4 zero4(){ f32x4 z = {0.f,0.f,0.f,0.f}; return z; }

// ------- merged prep: y<5 weight bf16-transpose, y==5 node qkv GEMV -------
__global__ void kprep(const float* wqkv_e, const float* e0_we, const float* e0_w1,
                      const float* e1_w1, const float* e1_w2,
                      const float* node, const float* wqkv_n,
                      unsigned short* WqkvT, unsigned short* WeT, unsigned short* W1T,
                      unsigned short* E1W1T, unsigned short* E1W2T,
                      float* qkvn){
  int m = blockIdx.y;
  int tid = threadIdx.x;
  if (m < 5){
    const float* src; unsigned short* dst; int K, Nn;
    if (m == 0){ src = wqkv_e; dst = WqkvT; K = 128; Nn = 512; }
    else if (m == 1){ src = e0_we; dst = WeT;   K = 256; Nn = 128; }
    else if (m == 2){ src = e0_w1; dst = W1T;   K = 128; Nn = 128; }
    else if (m == 3){ src = e1_w1; dst = E1W1T; K = 128; Nn = 256; }
    else            { src = e1_w2; dst = E1W2T; K = 256; Nn = 128; }
    int idx = blockIdx.x * 384 + tid;
    if (idx < K * Nn){
      int n = idx / K, k = idx % K;
      dst[idx] = f2bf(src[k * Nn + n]);
    }
  } else {
    int row = blockIdx.x;
    __shared__ float sn[128];
    if (tid < 128) sn[tid] = node[row * 128 + tid];
    __syncthreads();
    float acc = 0.f;
    #pragma unroll 8
    for (int k = 0; k < 128; ++k) acc += sn[k] * wqkv_n[k * 384 + tid];
    qkvn[row * 384 + tid] = acc;
  }
}

// ---------------- fused: edge fp32 -> bf16 + meanJ (contiguous row pass) ----------------
__global__ void kprepA(const float* __restrict__ edge, unsigned short* __restrict__ E16,
                       float* __restrict__ meanJ){
  __shared__ float red[8][128];
  int bi = blockIdx.x; int tid = threadIdx.x;
  const float4* src = (const float4*)(edge + (size_t)bi * N_ * D_);
  uint2* gdst = (uint2*)E16 + (size_t)bi * (N_ * D_ / 4);
  float ps0 = 0.f, ps1 = 0.f, ps2 = 0.f, ps3 = 0.f;
  #pragma unroll 4
  for (int k = 0; k < 48; ++k){
    int idx = k * 256 + tid;
    float4 v = src[idx];
    uint2 o;
    o.x = f2bf_pk(v.x, v.y);
    o.y = f2bf_pk(v.z, v.w);
    gdst[idx] = o;
    ps0 += v.x; ps1 += v.y; ps2 += v.z; ps3 += v.w;
  }
  int g = tid >> 5, d0 = (tid & 31) * 4;
  red[g][d0] = ps0; red[g][d0 + 1] = ps1; red[g][d0 + 2] = ps2; red[g][d0 + 3] = ps3;
  __syncthreads();
  if (tid < 128){
    float s = 0.f;
    #pragma unroll
    for (int gg = 0; gg < 8; ++gg) s += red[gg][tid];
    meanJ[bi * 128 + tid] = s * (1.0f / N_);
  }
}

// ---- merged: y==0 attention (2 heads/wave, prefetch), y==1 meanI column pass ----
__global__ __launch_bounds__(256, 2) void kattnI(
    const unsigned short* __restrict__ E16, const unsigned short* __restrict__ WqkvT,
    const float* __restrict__ qkvn, float* __restrict__ attn,
    float* __restrict__ meanI){
  __shared__ float red[16][128];
  int tid = threadIdx.x;
  if (blockIdx.y == 1){
    // ---------------- meanI over i, vectorized 16B loads ----------------
    int bj = blockIdx.x; int b = bj / N_, j = bj % N_;
    int ig = tid >> 4, dsub = tid & 15;
    float acc[8];
    #pragma unroll
    for (int e = 0; e < 8; ++e) acc[e] = 0.f;
    #pragma unroll 4
    for (int i = ig; i < N_; i += 16){
      const unsigned short* p = E16 + ((size_t)(b * N_ + i) * N_ + j) * D_ + dsub * 8;
      uint4 u = *(const uint4*)p;
      acc[0] += bf2f((unsigned short)(u.x & 0xffff)); acc[1] += bf2f((unsigned short)(u.x >> 16));
      acc[2] += bf2f((unsigned short)(u.y & 0xffff)); acc[3] += bf2f((unsigned short)(u.y >> 16));
      acc[4] += bf2f((unsigned short)(u.z & 0xffff)); acc[5] += bf2f((unsigned short)(u.z >> 16));
      acc[6] += bf2f((unsigned short)(u.w & 0xffff)); acc[7] += bf2f((unsigned short)(u.w >> 16));
    }
    #pragma unroll
    for (int e = 0; e < 8; ++e) red[ig][dsub * 8 + e] = acc[e];
    __syncthreads();
    if (tid < 128){
      float s = 0.f;
      #pragma unroll
      for (int gg = 0; gg < 16; ++gg) s += red[gg][tid];
      meanI[bj * 128 + tid] = s * (1.0f / N_);
    }
    return;
  }
  // ---------------- attention ----------------
  int bi = blockIdx.x; int b = bi / N_;
  int w = tid >> 6, lane = tid & 63, quad = lane >> 4, c16 = lane & 15;
  const float scale = 0.08838834764831845f;   // 1/sqrt(128)
  const unsigned short* Abase = E16 + (size_t)bi * N_ * D_;

  bh8 bf[2][4][4];
  #pragma unroll
  for (int s = 0; s < 2; ++s){
    int h = w + s * 4;
    #pragma unroll
    for (int u = 0; u < 4; ++u)
      #pragma unroll
      for (int ks = 0; ks < 4; ++ks){
        int col = h * 64 + u * 16 + c16;
        bf[s][u][ks] = *(const bh8*)(WqkvT + col * 128 + ks * 32 + quad * 8);
      }
  }
  float qv[2];
  #pragma unroll
  for (int s = 0; s < 2; ++s) qv[s] = qkvn[bi * 384 + (w + s * 4) * 48 + c16];

  float m_run[2] = {-1e30f, -1e30f}, l_run[2] = {0.f, 0.f}, o[2] = {0.f, 0.f};
  bh8 af[4];
  #pragma unroll
  for (int ks = 0; ks < 4; ++ks)
    af[ks] = *(const bh8*)(Abase + (size_t)c16 * D_ + ks * 32 + quad * 8);

  for (int jt = 0; jt < 24; ++jt){
    int jn = (jt + 1 < 24) ? jt + 1 : 0;
    bh8 afn[4];
    #pragma unroll
    for (int ks = 0; ks < 4; ++ks)
      afn[ks] = *(const bh8*)(Abase + (size_t)(jn * 16 + c16) * D_ + ks * 32 + quad * 8);
    float knv[2][4], vnv[2][4];
    const float* kvb = qkvn + ((size_t)b * N_ + jt * 16 + quad * 4) * 384;
    #pragma unroll
    for (int s = 0; s < 2; ++s)
      #pragma unroll
      for (int r = 0; r < 4; ++r){
        knv[s][r] = kvb[r * 384 + (w + s * 4) * 48 + 16 + c16];
        vnv[s][r] = kvb[r * 384 + (w + s * 4) * 48 + 32 + c16];
      }
    f32x4 EQ[2], EK[2], EV[2], EM[2];
    #pragma unroll
    for (int s = 0; s < 2; ++s){ EQ[s] = zero4(); EK[s] = zero4(); EV[s] = zero4(); EM[s] = zero4(); }
    #pragma unroll
    for (int ks = 0; ks < 4; ++ks)
      #pragma unroll
      for (int s = 0; s < 2; ++s){
        EQ[s] = mfma_bf16(af[ks], bf[s][0][ks], EQ[s]);
        EK[s] = mfma_bf16(af[ks], bf[s][1][ks], EK[s]);
        EV[s] = mfma_bf16(af[ks], bf[s][2][ks], EV[s]);
        EM[s] = mfma_bf16(af[ks], bf[s][3][ks], EM[s]);
      }
    #pragma unroll
    for (int s = 0; s < 2; ++s){
      float dots[4], vv[4];
      #pragma unroll
      for (int r = 0; r < 4; ++r){
        float t1 = (qv[s] + EQ[s][r]) * (knv[s][r] + EK[s][r]);
        t1 += __shfl_xor(t1, 1); t1 += __shfl_xor(t1, 2);
        t1 += __shfl_xor(t1, 4); t1 += __shfl_xor(t1, 8);
        dots[r] = t1 * scale;
        vv[r] = vnv[s][r] * EM[s][r] + EV[s][r];
      }
      float tmax = fmaxf(fmaxf(dots[0], dots[1]), fmaxf(dots[2], dots[3]));
      tmax = fmaxf(tmax, __shfl_xor(tmax, 16));
      tmax = fmaxf(tmax, __shfl_xor(tmax, 32));
      float mnew = fmaxf(m_run[s], tmax);
      float al = __expf(m_run[s] - mnew);
      float p0 = __expf(dots[0] - mnew), p1 = __expf(dots[1] - mnew);
      float p2 = __expf(dots[2] - mnew), p3 = __expf(dots[3] - mnew);
      float lt = p0 + p1 + p2 + p3;
      lt += __shfl_xor(lt, 16); lt += __shfl_xor(lt, 32);
      l_run[s] = l_run[s] * al + lt;
      m_run[s] = mnew;
      o[s] = o[s] * al + p0 * vv[0] + p1 * vv[1] + p2 * vv[2] + p3 * vv[3];
    }
    #pragma unroll
    for (int ks = 0; ks < 4; ++ks) af[ks] = afn[ks];
  }
  #pragma unroll
  for (int s = 0; s < 2; ++s){
    float oo = o[s];
    oo += __shfl_xor(oo, 16); oo += __shfl_xor(oo, 32);
    oo /= l_run[s];
    if (quad == 0) attn[(size_t)bi * D_ + (w + s * 4) * 16 + c16] = oo;
  }
}

// -------- merged node path: lin0+LN0+MLP+LN1 then rowAdd/colAdd GEMVs --------
__global__ void knodeadd(const float* __restrict__ node, const float* __restrict__ attn,
                         const float* lin0_w, const float* lin0_b,
                         const float* g0, const float* bb0,
                         const float* w1, const float* w2, const float* b2,
                         const float* g1, const float* bb1,
                         const float* __restrict__ meanJ, const float* __restrict__ meanI,
                         const float* ws, const float* bs, const float* wt, const float* bt,
                         const float* wer, const float* wec, const float* be,
                         float* __restrict__ xOut,
                         float* __restrict__ rowAdd, float* __restrict__ colAdd){
  int row = blockIdx.x; int tid = threadIdx.x;
  __shared__ float sa[128], sx[128], sh[256], rb[8], sx2[128], smJ[128], smI[128];
  if (tid < 128){
    sa[tid] = attn[row * 128 + tid];
    smJ[tid] = meanJ[row * 128 + tid];
    smI[tid] = meanI[row * 128 + tid];
  }
  __syncthreads();
  float y = 0.f, x0 = 0.f;
  if (tid < 128){
    float acc = lin0_b[tid];
    #pragma unroll 8
    for (int k = 0; k < 128; ++k) acc += sa[k] * lin0_w[k * 128 + tid];
    y = acc + node[row * 128 + tid];
  }
  { float sv = (tid < 128) ? y : 0.f, sq = (tid < 128) ? y * y : 0.f;
    #pragma unroll
    for (int m2 = 32; m2 >= 1; m2 >>= 1){ sv += __shfl_xor(sv, m2); sq += __shfl_xor(sq, m2); }
    if ((tid & 63) == 0){ rb[tid >> 6] = sv; rb[4 + (tid >> 6)] = sq; } }
  __syncthreads();
  float mean = (rb[0] + rb[1] + rb[2] + rb[3]) * (1.f / 128.f);
  float var  = (rb[4] + rb[5] + rb[6] + rb[7]) * (1.f / 128.f) - mean * mean;
  float rstd = rsqrtf(var + 1e-5f);
  if (tid < 128){ x0 = (y - mean) * rstd * g0[tid] + bb0[tid]; sx[tid] = x0; }
  __syncthreads();
  { float acc = 0.f;
    #pragma unroll 8
    for (int k = 0; k < 128; ++k) acc += sx[k] * w1[k * 256 + tid];
    sh[tid] = geluf(acc); }
  __syncthreads();
  float y2 = 0.f;
  if (tid < 128){
    float acc = b2[tid];
    #pragma unroll 8
    for (int e = 0; e < 256; ++e) acc += sh[e] * w2[e * 128 + tid];
    y2 = acc + x0;
  }
  __syncthreads();
  { float sv = (tid < 128) ? y2 : 0.f, sq = (tid < 128) ? y2 * y2 : 0.f;
    #pragma unroll
    for (int m2 = 32; m2 >= 1; m2 >>= 1){ sv += __shfl_xor(sv, m2); sq += __shfl_xor(sq, m2); }
    if ((tid & 63) == 0){ rb[tid >> 6] = sv; rb[4 + (tid >> 6)] = sq; } }
  __syncthreads();
  mean = (rb[0] + rb[1] + rb[2] + rb[3]) * (1.f / 128.f);
  var  = (rb[4] + rb[5] + rb[6] + rb[7]) * (1.f / 128.f) - mean * mean;
  rstd = rsqrtf(var + 1e-5f);
  if (tid < 128){
    float xv = (y2 - mean) * rstd * g1[tid] + bb1[tid];
    xOut[row * 128 + tid] = xv;
    sx2[tid] = xv;
  }
  __syncthreads();
  // ---- addends: tid<128 -> rowAdd (ws, wer); tid>=128 -> colAdd (wt, wec) ----
  if (tid < 128){
    int d = tid;
    float s1 = bs[d], s3 = 0.f;
    #pragma unroll 8
    for (int k = 0; k < 128; ++k){
      s1 += sx2[k] * ws[k * 128 + d];
      s3 += smJ[k] * wer[k * 128 + d];
    }
    rowAdd[row * 128 + d] = s1 + s3 + be[d];
  } else {
    int d = tid - 128;
    float s2 = bt[d], s4 = 0.f;
    #pragma unroll 8
    for (int k = 0; k < 128; ++k){
      s2 += sx2[k] * wt[k * 128 + d];
      s4 += smI[k] * wec[k * 128 + d];
    }
    colAdd[row * 128 + d] = s2 + s4;
  }
}

// -- fused edge pipeline v4: col-split + two-phase G3/G4, LDS=53248B -> 3 blocks/CU --
__global__ __launch_bounds__(256, 3) void kedge4(
    const unsigned short* __restrict__ E16, const unsigned short* __restrict__ WeT,
    const unsigned short* __restrict__ W1T, const unsigned short* __restrict__ E1W1T,
    const unsigned short* __restrict__ E1W2T,
    const float* __restrict__ rowAdd, const float* __restrict__ colAdd,
    const float* __restrict__ b1, const float* __restrict__ eg0, const float* __restrict__ eb0,
    const float* __restrict__ e1b2, const float* __restrict__ eg1, const float* __restrict__ eb1,
    float* __restrict__ eOut){
  __shared__ unsigned short sA[64][264];   // edge|edgeT; cols 0..127 become edge2 after LN0
  __shared__ unsigned short sT[64][136];   // 128-wide stage buffer
  __shared__ float lrS[4][64], lrQ[4][64]; // total LDS = 33792+17408+2048 = 53248 B
  int tid = threadIdx.x;
  int w = tid >> 6, lane = tid & 63, quad = lane >> 4, c16 = lane & 15;
  int R0 = blockIdx.x * 64;
  int b = R0 / NN; int rem = R0 % NN; int i = rem / N_; int j0 = rem % N_;

  // ---- prefetch G1 weights + epilogue addends ----
  bh8 wb1[2][8];
  #pragma unroll
  for (int t = 0; t < 2; ++t)
    #pragma unroll
    for (int ks = 0; ks < 8; ++ks){
      int col = w * 32 + t * 16 + c16;
      wb1[t][ks] = *(const bh8*)(WeT + (size_t)col * 256 + ks * 32 + quad * 8);
    }
  float ca[2][16], rAv[2];
  #pragma unroll
  for (int t = 0; t < 2; ++t){
    rAv[t] = rowAdd[(b * N_ + i) * D_ + w * 32 + t * 16 + c16];
    #pragma unroll
    for (int ms = 0; ms < 4; ++ms)
      #pragma unroll
      for (int r = 0; r < 4; ++r)
        ca[t][ms * 4 + r] = colAdd[(size_t)(b * N_ + j0 + ms * 16 + quad * 4 + r) * D_
                                   + w * 32 + t * 16 + c16];
  }

  // ---- stage A = [edge(b,i,j0+m,:) | edge(b,j0+m,i,:)] bf16, 64x256 ----
  #pragma unroll
  for (int it = 0; it < 8; ++it){
    int cid = it * 256 + tid;
    int rrow = cid >> 5;
    int kc = (cid & 31) * 8;
    const unsigned short* sp;
    if (kc < 128) sp = E16 + ((size_t)(b * N_ + i) * N_ + (j0 + rrow)) * D_ + kc;
    else          sp = E16 + ((size_t)(b * N_ + j0 + rrow) * N_ + i) * D_ + (kc - 128);
    *(float4*)&sA[rrow][kc] = *(const float4*)sp;
  }
  __syncthreads();

  // ---- G1: A(64x256) @ WeT^T -> cols [32w,32w+32); +rowAdd+colAdd, gelu -> sT ----
  f32x4 acc1[2][4];
  #pragma unroll
  for (int t = 0; t < 2; ++t) for (int ms = 0; ms < 4; ++ms) acc1[t][ms] = zero4();
  #pragma unroll
  for (int ks = 0; ks < 8; ++ks){
    bh8 af[4];
    #pragma unroll
    for (int ms = 0; ms < 4; ++ms)
      af[ms] = *(const bh8*)&sA[ms * 16 + c16][ks * 32 + quad * 8];
    #pragma unroll
    for (int t = 0; t < 2; ++t)
      #pragma unroll
      for (int ms = 0; ms < 4; ++ms)
        acc1[t][ms] = mfma_bf16(af[ms], wb1[t][ks], acc1[t][ms]);
  }
  #pragma unroll
  for (int ms = 0; ms < 4; ++ms)
    #pragma unroll
    for (int r = 0; r < 4; ++r){
      int m = ms * 16 + quad * 4 + r;
      float v0 = gelu_fast(acc1[0][ms][r] + rAv[0] + ca[0][ms * 4 + r]);
      float v1 = gelu_fast(acc1[1][ms][r] + rAv[1] + ca[1][ms * 4 + r]);
      unsigned pk = f2bf_pk(v0, v1);
      sT[m][w * 32 + c16] = (unsigned short)(pk & 0xffff);
      sT[m][w * 32 + 16 + c16] = (unsigned short)(pk >> 16);
    }
  __syncthreads();

  // ---- G2: gelu1 @ W1T^T + b1 + edge(bf16, sA) -> LN0 partials ----
  bh8 wb2[2][4];
  #pragma unroll
  for (int t = 0; t < 2; ++t)
    #pragma unroll
    for (int ks = 0; ks < 4; ++ks){
      int col = w * 32 + t * 16 + c16;
      wb2[t][ks] = *(const bh8*)(W1T + (size_t)col * 128 + ks * 32 + quad * 8);
    }
  f32x4 acc2[2][4];
  #pragma unroll
  for (int t = 0; t < 2; ++t) for (int ms = 0; ms < 4; ++ms) acc2[t][ms] = zero4();
  #pragma unroll
  for (int ks = 0; ks < 4; ++ks){
    bh8 af[4];
    #pragma unroll
    for (int ms = 0; ms < 4; ++ms)
      af[ms] = *(const bh8*)&sT[ms * 16 + c16][ks * 32 + quad * 8];
    #pragma unroll
    for (int t = 0; t < 2; ++t)
      #pragma unroll
      for (int ms = 0; ms < 4; ++ms)
        acc2[t][ms] = mfma_bf16(af[ms], wb2[t][ks], acc2[t][ms]);
  }
  float b1v[2], g0v[2], b0v[2];
  #pragma unroll
  for (int t = 0; t < 2; ++t){
    int c = w * 32 + t * 16 + c16;
    b1v[t] = b1[c]; g0v[t] = eg0[c]; b0v[t] = eb0[c];
  }
  #pragma unroll
  for (int ms = 0; ms < 4; ++ms)
    #pragma unroll
    for (int r = 0; r < 4; ++r){
      int m = ms * 16 + quad * 4 + r;
      float s = 0.f, q = 0.f;
      #pragma unroll
      for (int t = 0; t < 2; ++t){
        float v = acc2[t][ms][r] + b1v[t] + bf2f(sA[m][w * 32 + t * 16 + c16]);
        acc2[t][ms][r] = v; s += v; q += v * v;
      }
      s += __shfl_xor(s, 1); s += __shfl_xor(s, 2); s += __shfl_xor(s, 4); s += __shfl_xor(s, 8);
      q += __shfl_xor(q, 1); q += __shfl_xor(q, 2); q += __shfl_xor(q, 4); q += __shfl_xor(q, 8);
      if (c16 == 0){ lrS[w][m] = s; lrQ[w][m] = q; }
    }
  __syncthreads();

  // ---- LN0 finalize -> edge2 bf16 into sA cols 0..127 ----
  #pragma unroll
  for (int ms = 0; ms < 4; ++ms)
    #pragma unroll
    for (int r = 0; r < 4; ++r){
      int m = ms * 16 + quad * 4 + r;
      float s = lrS[0][m] + lrS[1][m] + lrS[2][m] + lrS[3][m];
      float q = lrQ[0][m] + lrQ[1][m] + lrQ[2][m] + lrQ[3][m];
      float mean = s * (1.f / 128.f);
      float var  = q * (1.f / 128.f) - mean * mean;
      float rstd = rsqrtf(var + 1e-5f);
      float e0 = (acc2[0][ms][r] - mean) * rstd * g0v[0] + b0v[0];
      float e1 = (acc2[1][ms][r] - mean) * rstd * g0v[1] + b0v[1];
      unsigned pk = f2bf_pk(e0, e1);
      sA[m][w * 32 + c16] = (unsigned short)(pk & 0xffff);
      sA[m][w * 32 + 16 + c16] = (unsigned short)(pk >> 16);
    }
  __syncthreads();

  // ---- G3/G4 two-phase over K=256: per phase G3 (128 cols) -> gelu -> sT -> G4 partial ----
  f32x4 acc4[2][4];
  #pragma unroll
  for (int t = 0; t < 2; ++t) for (int ms = 0; ms < 4; ++ms) acc4[t][ms] = zero4();
  #pragma unroll
  for (int p = 0; p < 2; ++p){
    // G3 phase p: edge2 @ E1W1T^T cols [p*128 + 32w, +32)
    bh8 wb3[2][4];
    #pragma unroll
    for (int t = 0; t < 2; ++t)
      #pragma unroll
      for (int ks = 0; ks < 4; ++ks){
        int col = p * 128 + w * 32 + t * 16 + c16;
        wb3[t][ks] = *(const bh8*)(E1W1T + (size_t)col * 128 + ks * 32 + quad * 8);
      }
    f32x4 acc3[2][4];
    #pragma unroll
    for (int t = 0; t < 2; ++t) for (int ms = 0; ms < 4; ++ms) acc3[t][ms] = zero4();
    #pragma unroll
    for (int ks = 0; ks < 4; ++ks){
      bh8 af[4];
      #pragma unroll
      for (int ms = 0; ms < 4; ++ms)
        af[ms] = *(const bh8*)&sA[ms * 16 + c16][ks * 32 + quad * 8];
      #pragma unroll
      for (int t = 0; t < 2; ++t)
        #pragma unroll
        for (int ms = 0; ms < 4; ++ms)
          acc3[t][ms] = mfma_bf16(af[ms], wb3[t][ks], acc3[t][ms]);
    }
    #pragma unroll
    for (int ms = 0; ms < 4; ++ms)
      #pragma unroll
      for (int r = 0; r < 4; ++r){
        int m = ms * 16 + quad * 4 + r;
        float v0 = gelu_fast(acc3[0][ms][r]);
        float v1 = gelu_fast(acc3[1][ms][r]);
        unsigned pk = f2bf_pk(v0, v1);
        sT[m][w * 32 + c16] = (unsigned short)(pk & 0xffff);
        sT[m][w * 32 + 16 + c16] = (unsigned short)(pk >> 16);
      }
    __syncthreads();
    // G4 partial: gelu3(p) @ E1W2T^T K-slice [p*128, p*128+128)
    bh8 wb4[2][4];
    #pragma unroll
    for (int t = 0; t < 2; ++t)
      #pragma unroll
      for (int k2 = 0; k2 < 4; ++k2){
        int col = w * 32 + t * 16 + c16;
        wb4[t][k2] = *(const bh8*)(E1W2T + (size_t)col * 256 + p * 128 + k2 * 32 + quad * 8);
      }
    #pragma unroll
    for (int k2 = 0; k2 < 4; ++k2){
      bh8 af[4];
      #pragma unroll
      for (int ms = 0; ms < 4; ++ms)
        af[ms] = *(const bh8*)&sT[ms * 16 + c16][k2 * 32 + quad * 8];
      #pragma unroll
      for (int t = 0; t < 2; ++t)
        #pragma unroll
        for (int ms = 0; ms < 4; ++ms)
          acc4[t][ms] = mfma_bf16(af[ms], wb4[t][k2], acc4[t][ms]);
    }
    __syncthreads();
  }

  // ---- G4 epilogue: + b2 + edge2(bf16, sA) -> LN1 -> store ----
  float b2v[2], g1v[2], bb1v[2];
  #pragma unroll
  for (int t = 0; t < 2; ++t){
    int c = w * 32 + t * 16 + c16;
    b2v[t] = e1b2[c]; g1v[t] = eg1[c]; bb1v[t] = eb1[c];
  }
  #pragma unroll
  for (int ms = 0; ms < 4; ++ms)
    #pragma unroll
    for (int r = 0; r < 4; ++r){
      int m = ms * 16 + quad * 4 + r;
      float s = 0.f, q = 0.f;
      #pragma unroll
      for (int t = 0; t < 2; ++t){
        float v = acc4[t][ms][r] + b2v[t] + bf2f(sA[m][w * 32 + t * 16 + c16]);
        acc4[t][ms][r] = v; s += v; q += v * v;
      }
      s += __shfl_xor(s, 1); s += __shfl_xor(s, 2); s += __shfl_xor(s, 4); s += __shfl_xor(s, 8);
      q += __shfl_xor(q, 1); q += __shfl_xor(q, 2); q += __shfl_xor(q, 4); q += __shfl_xor(q, 8);
      if (c16 == 0){ lrS[w][m] = s; lrQ[w][m] = q; }
    }
  __syncthreads();
  float* outBase = eOut + ((size_t)(b * N_ + i) * N_ + j0) * D_;
  #pragma unroll
  for (int ms = 0; ms < 4; ++ms)
    #pragma unroll
    for (int r = 0; r < 4; ++r){
      int m = ms * 16 + quad * 4 + r;
      float s = lrS[0][m] + lrS[1][m] + lrS[2][m] + lrS[3][m];
      float q = lrQ[0][m] + lrQ[1][m] + lrQ[2][m] + lrQ[3][m];
      float mean = s * (1.f / 128.f);
      float var  = q * (1.f / 128.f) - mean * mean;
      float rstd = rsqrtf(var + 1e-5f);
      #pragma unroll
      for (int t = 0; t < 2; ++t){
        int c = w * 32 + t * 16 + c16;
        outBase[(size_t)m * D_ + c] = (acc4[t][ms][r] - mean) * rstd * g1v[t] + bb1v[t];
      }
    }
}

extern "C" void kernel_launch(void* const* d_in, const int* in_sizes, int n_in,
                              void* d_out, int out_size, void* d_ws, size_t ws_size,
                              hipStream_t stream){
  const float* node   = (const float*)d_in[0];
  const float* edge   = (const float*)d_in[1];
  const float* wqkv_n = (const float*)d_in[3];
  const float* wqkv_e = (const float*)d_in[4];
  const float* lin0_w = (const float*)d_in[5];
  const float* lin0_b = (const float*)d_in[6];
  const float* ln0_g  = (const float*)d_in[7];
  const float* ln0_b  = (const float*)d_in[8];
  const float* ln1_g  = (const float*)d_in[9];
  const float* ln1_b  = (const float*)d_in[10];
  const float* nmlp_w1= (const float*)d_in[11];
  const float* nmlp_w2= (const float*)d_in[12];
  const float* nmlp_b2= (const float*)d_in[13];
  const float* e0_we  = (const float*)d_in[14];
  const float* e0_be  = (const float*)d_in[15];
  const float* e0_ws  = (const float*)d_in[16];
  const float* e0_bs  = (const float*)d_in[17];
  const float* e0_wt  = (const float*)d_in[18];
  const float* e0_bt  = (const float*)d_in[19];
  const float* e0_wer = (const float*)d_in[20];
  const float* e0_wec = (const float*)d_in[21];
  const float* e0_w1  = (const float*)d_in[22];
  const float* e0_b1  = (const float*)d_in[23];
  const float* e1_w1  = (const float*)d_in[24];
  const float* e1_w2  = (const float*)d_in[25];
  const float* e1_b2  = (const float*)d_in[26];
  const float* eln0_g = (const float*)d_in[27];
  const float* eln0_b = (const float*)d_in[28];
  const float* eln1_g = (const float*)d_in[29];
  const float* eln1_b = (const float*)d_in[30];

  unsigned short* E16   = (unsigned short*)d_ws;
  unsigned short* WqkvT = E16 + (size_t)EDGE_ELEMS;
  unsigned short* WeT   = WqkvT + 65536;
  unsigned short* W1T   = WeT + 32768;
  unsigned short* E1W1T = W1T + 16384;
  unsigned short* E1W2T = E1W1T + 32768;
  float* fbase  = (float*)(E1W2T + 32768);
  float* qkvn   = fbase;
  float* attn   = qkvn + (size_t)BN * 384;
  float* meanJ  = attn + NODE_ELEMS;
  float* meanI  = meanJ + NODE_ELEMS;
  float* rowAdd = meanI + NODE_ELEMS;
  float* colAdd = rowAdd + NODE_ELEMS;

  float* xOut = (float*)d_out;
  float* eOut = xOut + NODE_ELEMS;

  kprep<<<dim3(BN, 6), 384, 0, stream>>>(wqkv_e, e0_we, e0_w1, e1_w1, e1_w2,
                                         node, wqkv_n,
                                         WqkvT, WeT, W1T, E1W1T, E1W2T, qkvn);
  kprepA<<<BN, 256, 0, stream>>>(edge, E16, meanJ);
  kattnI<<<dim3(BN, 2), 256, 0, stream>>>(E16, WqkvT, qkvn, attn, meanI);
  knodeadd<<<BN, 256, 0, stream>>>(node, attn, lin0_w, lin0_b, ln0_g, ln0_b,
                                   nmlp_w1, nmlp_w2, nmlp_b2, ln1_g, ln1_b,
                                   meanJ, meanI, e0_ws, e0_bs, e0_wt, e0_bt,
                                   e0_wer, e0_wec, e0_be,
                                   xOut, rowAdd, colAdd);
  kedge4<<<NN * B_ / 64, 256, 0, stream>>>(E16, WeT, W1T, E1W1T, E1W2T,
                                           rowAdd, colAdd, e0_b1,
                                           eln0_g, eln0_b, e1_b2, eln1_g, eln1_b,
                                           eOut);
}